// Round 8
// baseline (388.480 us; speedup 1.0000x reference)
//
#include <hip/hip_runtime.h>
#include <hip/hip_bf16.h>

#define B_ 4
#define T_ 2048
#define C_ 1024
#define H_ 16
#define D_ 64
#define M_ (B_*T_)   // 8192

typedef __bf16 bf16x8 __attribute__((ext_vector_type(8)));
typedef float  f32x4  __attribute__((ext_vector_type(4)));
typedef float  f32x16 __attribute__((ext_vector_type(16)));

__device__ __forceinline__ unsigned short f2bf(float f) {
  unsigned u = __builtin_bit_cast(unsigned, f);
  u += 0x7FFF + ((u >> 16) & 1);   // round-to-nearest-even
  return (unsigned short)(u >> 16);
}

__device__ __forceinline__ void gload_lds16(const void* g, void* l) {
  __builtin_amdgcn_global_load_lds(
      (const __attribute__((address_space(1))) void*)g,
      (__attribute__((address_space(3))) void*)l, 16, 0, 0);
}

// ---------------- conversion: f32 -> bf16 (vectorized) ----------------
__global__ void cvt_f32_bf16(const float* __restrict__ in,
                             unsigned short* __restrict__ out, int n4) {
  int i = blockIdx.x * blockDim.x + threadIdx.x;
  if (i < n4) {
    float4 v = ((const float4*)in)[i];
    ushort4 o;
    o.x = f2bf(v.x); o.y = f2bf(v.y); o.z = f2bf(v.z); o.w = f2bf(v.w);
    ((ushort4*)out)[i] = o;
  }
}

// ------------- weight transpose + convert: W[K][N] f32 -> Wt[N][K] bf16 -------------
__global__ void transpose_cvt(const float* __restrict__ w0, const float* __restrict__ w1,
                              const float* __restrict__ w2, const float* __restrict__ w3,
                              unsigned short* __restrict__ tqkv,
                              unsigned short* __restrict__ tp) {
  __shared__ float tile[32][33];
  const float* src; unsigned short* dst;
  switch (blockIdx.z) {
    case 0: src = w0; dst = tqkv; break;
    case 1: src = w1; dst = tqkv + (size_t)C_ * C_; break;
    case 2: src = w2; dst = tqkv + (size_t)2 * C_ * C_; break;
    default: src = w3; dst = tp; break;
  }
  int bx = blockIdx.x * 32;  // n base
  int by = blockIdx.y * 32;  // k base
  int tx = threadIdx.x, ty = threadIdx.y;
  #pragma unroll
  for (int j = 0; j < 4; ++j)
    tile[ty + 8*j][tx] = src[(size_t)(by + ty + 8*j) * C_ + bx + tx];
  __syncthreads();
  #pragma unroll
  for (int j = 0; j < 4; ++j)
    dst[(size_t)(bx + ty + 8*j) * C_ + by + tx] = f2bf(tile[tx][ty + 8*j]);
}

// ---------------- fused QKV GEMM: xb[M][K] @ wqkvt[3N][K]^T ----------------
__global__ __launch_bounds__(256, 2)
void gemm_qkv(const unsigned short* __restrict__ A,
              const unsigned short* __restrict__ Bt,
              const float* __restrict__ bq, const float* __restrict__ bk,
              const float* __restrict__ bv,
              unsigned short* __restrict__ qout, unsigned short* __restrict__ kout,
              unsigned short* __restrict__ vout, float qscale)
{
  __shared__ unsigned short lsA[128 * 64];
  __shared__ unsigned short lsB[128 * 64];
  const int wave = threadIdx.x >> 6;
  const int lane = threadIdx.x & 63;
  const int rowBase = blockIdx.y * 128;
  const int colBase = blockIdx.x * 128;
  const int rowOff = (wave >> 1) * 64;
  const int colOff = (wave & 1) * 64;
  const int lr = lane & 15;
  const int lg = lane >> 4;

  f32x4 acc[4][4] = {};

  const int chunkRow = lane >> 3;
  const int srcColE  = (((lane & 7) ^ (lane >> 3)) * 8);

  for (int k0 = 0; k0 < C_; k0 += 64) {
    #pragma unroll
    for (int c = 0; c < 4; ++c) {
      int chunk = c * 4 + wave;
      int r = chunk * 8 + chunkRow;
      gload_lds16(A  + (size_t)(rowBase + r) * C_ + k0 + srcColE, &lsA[chunk * 512]);
      gload_lds16(Bt + (size_t)(colBase + r) * C_ + k0 + srcColE, &lsB[chunk * 512]);
    }
    __syncthreads();
    #pragma unroll
    for (int kk = 0; kk < 2; ++kk) {
      bf16x8 af[4], bfr[4];
      const int kbyte = (kk * 32 + lg * 8) * 2;
      #pragma unroll
      for (int m = 0; m < 4; ++m) {
        int row = rowOff + m * 16 + lr;
        af[m] = *(const bf16x8*)((const char*)lsA + row * 128 + (kbyte ^ ((row & 7) << 4)));
      }
      #pragma unroll
      for (int n = 0; n < 4; ++n) {
        int row = colOff + n * 16 + lr;
        bfr[n] = *(const bf16x8*)((const char*)lsB + row * 128 + (kbyte ^ ((row & 7) << 4)));
      }
      #pragma unroll
      for (int m = 0; m < 4; ++m)
        #pragma unroll
        for (int n = 0; n < 4; ++n)
          acc[m][n] = __builtin_amdgcn_mfma_f32_16x16x32_bf16(af[m], bfr[n], acc[m][n], 0, 0, 0);
    }
    __syncthreads();
  }

  const int mid = colBase >> 10;                 // 0=Q 1=K 2=V (block-uniform)
  const float* bias = (mid == 0) ? bq : (mid == 1) ? bk : bv;
  const float oscale = (mid == 0) ? qscale : 1.f;
  unsigned short* outp = (mid == 0) ? qout : (mid == 1) ? kout : vout;

  #pragma unroll
  for (int m = 0; m < 4; ++m) {
    int row0 = rowBase + rowOff + m * 16 + lg * 4;
    #pragma unroll
    for (int n = 0; n < 4; ++n) {
      int col = colBase + colOff + n * 16 + lr;
      int ncol = col & 1023;
      float bs = bias[ncol];
      int h = ncol >> 6, d = ncol & 63;
      if (mid == 2) {
        int b = row0 >> 11, t = row0 & 2047;
        int t2 = (t & ~12) | ((t & 4) << 1) | ((t & 8) >> 1);  // key-perm (bits 2<->3)
        ushort4 o;
        o.x = f2bf(acc[m][n][0] + bs);
        o.y = f2bf(acc[m][n][1] + bs);
        o.z = f2bf(acc[m][n][2] + bs);
        o.w = f2bf(acc[m][n][3] + bs);
        *(ushort4*)(outp + (((size_t)b * H_ + h) * D_ + d) * T_ + t2) = o;
      } else {
        #pragma unroll
        for (int j = 0; j < 4; ++j) {
          int r = row0 + j;
          int b = r >> 11, t = r & 2047;
          outp[((((size_t)b * H_ + h) * T_ + t) << 6) + d] = f2bf((acc[m][n][j] + bs) * oscale);
        }
      }
    }
  }
}

// ---------------- final projection GEMM: yb[M][K] @ wpt[N][K]^T -> f32 ----------------
__global__ __launch_bounds__(256, 2)
void gemm_proj(const unsigned short* __restrict__ A,
               const unsigned short* __restrict__ Bt,
               const float* __restrict__ bias,
               float* __restrict__ Cout)
{
  __shared__ unsigned short lsA[128 * 64];
  __shared__ unsigned short lsB[128 * 64];
  const int wave = threadIdx.x >> 6;
  const int lane = threadIdx.x & 63;
  const int rowBase = blockIdx.y * 128;
  const int colBase = blockIdx.x * 128;
  const int rowOff = (wave >> 1) * 64;
  const int colOff = (wave & 1) * 64;
  const int lr = lane & 15;
  const int lg = lane >> 4;

  f32x4 acc[4][4] = {};

  const int chunkRow = lane >> 3;
  const int srcColE  = (((lane & 7) ^ (lane >> 3)) * 8);

  for (int k0 = 0; k0 < C_; k0 += 64) {
    #pragma unroll
    for (int c = 0; c < 4; ++c) {
      int chunk = c * 4 + wave;
      int r = chunk * 8 + chunkRow;
      gload_lds16(A  + (size_t)(rowBase + r) * C_ + k0 + srcColE, &lsA[chunk * 512]);
      gload_lds16(Bt + (size_t)(colBase + r) * C_ + k0 + srcColE, &lsB[chunk * 512]);
    }
    __syncthreads();
    #pragma unroll
    for (int kk = 0; kk < 2; ++kk) {
      bf16x8 af[4], bfr[4];
      const int kbyte = (kk * 32 + lg * 8) * 2;
      #pragma unroll
      for (int m = 0; m < 4; ++m) {
        int row = rowOff + m * 16 + lr;
        af[m] = *(const bf16x8*)((const char*)lsA + row * 128 + (kbyte ^ ((row & 7) << 4)));
      }
      #pragma unroll
      for (int n = 0; n < 4; ++n) {
        int row = colOff + n * 16 + lr;
        bfr[n] = *(const bf16x8*)((const char*)lsB + row * 128 + (kbyte ^ ((row & 7) << 4)));
      }
      #pragma unroll
      for (int m = 0; m < 4; ++m)
        #pragma unroll
        for (int n = 0; n < 4; ++n)
          acc[m][n] = __builtin_amdgcn_mfma_f32_16x16x32_bf16(af[m], bfr[n], acc[m][n], 0, 0, 0);
    }
    __syncthreads();
  }

  #pragma unroll
  for (int m = 0; m < 4; ++m) {
    int row0 = rowBase + rowOff + m * 16 + lg * 4;
    #pragma unroll
    for (int n = 0; n < 4; ++n) {
      int col = colBase + colOff + n * 16 + lr;
      float bs = bias[col];
      #pragma unroll
      for (int j = 0; j < 4; ++j)
        Cout[(size_t)(row0 + j) * C_ + col] = acc[m][n][j] + bs;
    }
  }
}

// ---------------- causal flash attention: 4-way KV-split per q-tile ----------------
// q,k: [B][H][T][D] bf16 (q pre-scaled by log2e/sqrt(D)); vp: [B][H][D][T] bf16 key-permuted
// (bits 2<->3 of t swapped) so global layout == MFMA A-fragment layout; y: [B][T][C] bf16.
// One BLOCK per 32-row q-tile (4096 blocks); its 4 waves each process a contiguous quarter
// of the causal KV range with independent online-softmax state, then merge via LDS:
// M = max m_w ; O = sum exp2(m_w - M) O_w ; l = sum exp2(m_w - M) l_w.  No barrier in the
// KV loop; register pipeline per tile as in attn7. 16 waves/CU resident (VGPR<=128).
__global__ __launch_bounds__(256, 4)
void attn8(const unsigned short* __restrict__ q,
           const unsigned short* __restrict__ k,
           const unsigned short* __restrict__ vp,
           unsigned short* __restrict__ y)
{
  __shared__ float cbuf[3][64][36];   // partials of waves 1..3 (27.6 KB)
  const int wave = threadIdx.x >> 6;
  const int lane = threadIdx.x & 63;
  const int col  = lane & 31;   // query index within 32 (and K-row / V-d-row index)
  const int hi   = lane >> 5;

  // decode: 4096 blocks = 8 xcd * 8 heads * 64 q-tiles; longest q-tiles first
  const int bid = blockIdx.x;
  const int xcd = bid & 7;
  const int r   = bid >> 3;              // 0..511
  const int bh  = xcd * 8 + (r & 7);     // 8 heads per XCD
  const int qt  = 63 - (r >> 3);         // 63..0 (longest first)
  const int q0  = qt * 32;
  const int ntiles = qt + 1;
  const int b = bh >> 4, h = bh & 15;

  // this wave's contiguous KV chunk [s0, s0+cnt)
  const int base = ntiles >> 2, rem = ntiles & 3;
  const int cnt  = base + (wave < rem ? 1 : 0);
  const int s0   = wave * base + (wave < rem ? wave : rem);
  const bool dg  = (s0 + cnt == ntiles);   // owns the diagonal tile

  const unsigned short* qh = q  + (size_t)bh * T_ * D_;
  const unsigned short* kh = k  + (size_t)bh * T_ * D_;
  const unsigned short* vh = vp + (size_t)bh * D_ * T_;

  // Q B-fragments: bqf[ks] = Q[q0+col][ks*16 + hi*8 + e]
  bf16x8 bqf[4];
  {
    const unsigned short* qrow = qh + (size_t)(q0 + col) * D_ + hi * 8;
    #pragma unroll
    for (int ks = 0; ks < 4; ++ks) bqf[ks] = *(const bf16x8*)(qrow + ks * 16);
  }

  f32x16 ot0 = {}, ot1 = {};
  float m = -INFINITY, l = 0.f;
  const f32x16 zc = {};

  if (cnt > 0) {
    bf16x8 kfA[4], kfB[4], vf[4];
    f32x16 S0, S1;
    bf16x8 pf0, pf1;

    const unsigned short* kbase = kh + (size_t)col * D_ + hi * 8 + (size_t)s0 * 32 * D_;
    const unsigned short* vbase = vh + (size_t)col * T_ + hi * 8 + s0 * 32;
    const unsigned short* kld = kbase + 2 * 32 * D_;   // next K load: rel tile 2
    const unsigned short* vld = vbase + 32;            // next V load: rel tile 1

    // prologue: K0, V0, K1; S0 = QK^T(rel tile 0)
    #pragma unroll
    for (int ks = 0; ks < 4; ++ks) kfA[ks] = *(const bf16x8*)(kbase + ks * 16);
    #pragma unroll
    for (int dt = 0; dt < 2; ++dt)
      #pragma unroll
      for (int ks = 0; ks < 2; ++ks)
        vf[dt * 2 + ks] = *(const bf16x8*)(vbase + dt * 32 * T_ + ks * 16);
    if (cnt > 1) {
      #pragma unroll
      for (int ks = 0; ks < 4; ++ks) kfB[ks] = *(const bf16x8*)(kbase + 32 * D_ + ks * 16);
    }
    S0 = __builtin_amdgcn_mfma_f32_32x32x16_bf16(kfA[0], bqf[0], zc, 0, 0, 0);
    S0 = __builtin_amdgcn_mfma_f32_32x32x16_bf16(kfA[1], bqf[1], S0, 0, 0, 0);
    S0 = __builtin_amdgcn_mfma_f32_32x32x16_bf16(kfA[2], bqf[2], S0, 0, 0, 0);
    S0 = __builtin_amdgcn_mfma_f32_32x32x16_bf16(kfA[3], bqf[3], S0, 0, 0, 0);

    int t = 0;   // relative tile index

    auto SOFTMAX = [&](f32x16& S, bool diag) {
      if (diag) {
        #pragma unroll
        for (int rr = 0; rr < 16; ++rr) {
          int key = (s0 + t) * 32 + (rr & 3) + 8 * (rr >> 2) + 4 * hi;
          if (key > q0 + col) S[rr] = -INFINITY;
        }
      }
      float a0 = fmaxf(fmaxf(S[0], S[1]), fmaxf(S[2], S[3]));
      float a1 = fmaxf(fmaxf(S[4], S[5]), fmaxf(S[6], S[7]));
      float a2 = fmaxf(fmaxf(S[8], S[9]), fmaxf(S[10], S[11]));
      float a3 = fmaxf(fmaxf(S[12], S[13]), fmaxf(S[14], S[15]));
      float mm = fmaxf(fmaxf(a0, a1), fmaxf(a2, a3));
      mm = fmaxf(mm, __shfl_xor(mm, 32));
      if (!__all(mm <= m + 8.f)) {           // defer-max THR=8 (exp2 domain)
        float mnew = fmaxf(m, mm);
        float corr = exp2f(m - mnew);
        m = mnew;
        l *= corr;
        #pragma unroll
        for (int rr = 0; rr < 16; ++rr) { ot0[rr] *= corr; ot1[rr] *= corr; }
      }
      float pa[8], pb[8];
      {
        bf16x8 w;
        #pragma unroll
        for (int e = 0; e < 8; ++e) { pa[e] = exp2f(S[e] - m);     w[e] = (__bf16)pa[e]; }
        pf0 = w;
      }
      {
        bf16x8 w;
        #pragma unroll
        for (int e = 0; e < 8; ++e) { pb[e] = exp2f(S[8 + e] - m); w[e] = (__bf16)pb[e]; }
        pf1 = w;
      }
      float sA = (pa[0] + pa[1]) + (pa[2] + pa[3]);
      float sB = (pa[4] + pa[5]) + (pa[6] + pa[7]);
      float sC = (pb[0] + pb[1]) + (pb[2] + pb[3]);
      float sD = (pb[4] + pb[5]) + (pb[6] + pb[7]);
      float psum = (sA + sB) + (sC + sD);
      psum += __shfl_xor(psum, 32);
      l += psum;
    };

    auto PVSTEP = [&]() {
      __builtin_amdgcn_s_setprio(1);
      ot0 = __builtin_amdgcn_mfma_f32_32x32x16_bf16(vf[0], pf0, ot0, 0, 0, 0);
      ot1 = __builtin_amdgcn_mfma_f32_32x32x16_bf16(vf[2], pf0, ot1, 0, 0, 0);
      ot0 = __builtin_amdgcn_mfma_f32_32x32x16_bf16(vf[1], pf1, ot0, 0, 0, 0);
      ot1 = __builtin_amdgcn_mfma_f32_32x32x16_bf16(vf[3], pf1, ot1, 0, 0, 0);
      __builtin_amdgcn_s_setprio(0);
    };

#define STEP(KN, KL, SCUR, SNEW)                                                    \
    do {                                                                            \
      __builtin_amdgcn_s_setprio(1);                                                \
      SNEW = __builtin_amdgcn_mfma_f32_32x32x16_bf16(KN[0], bqf[0], zc,   0, 0, 0); \
      SNEW = __builtin_amdgcn_mfma_f32_32x32x16_bf16(KN[1], bqf[1], SNEW, 0, 0, 0); \
      SNEW = __builtin_amdgcn_mfma_f32_32x32x16_bf16(KN[2], bqf[2], SNEW, 0, 0, 0); \
      SNEW = __builtin_amdgcn_mfma_f32_32x32x16_bf16(KN[3], bqf[3], SNEW, 0, 0, 0); \
      __builtin_amdgcn_s_setprio(0);                                                \
      if (t + 2 < cnt) {                                                            \
        _Pragma("unroll")                                                           \
        for (int ks = 0; ks < 4; ++ks) KL[ks] = *(const bf16x8*)(kld + ks * 16);    \
        kld += 32 * D_;                                                             \
      }                                                                             \
      SOFTMAX(SCUR, false);                                                         \
      PVSTEP();                                                                     \
      _Pragma("unroll")                                                             \
      for (int dt = 0; dt < 2; ++dt) {                                              \
        _Pragma("unroll")                                                           \
        for (int ks = 0; ks < 2; ++ks)                                              \
          vf[dt * 2 + ks] = *(const bf16x8*)(vld + dt * 32 * T_ + ks * 16);         \
      }                                                                             \
      vld += 32;                                                                    \
      ++t;                                                                          \
    } while (0)

    if (cnt == 1) {
      SOFTMAX(S0, dg);
      PVSTEP();
    } else {
      bool done = false;
      while (!done) {
        STEP(kfB, kfA, S0, S1);
        if (t + 1 >= cnt) { SOFTMAX(S1, dg); PVSTEP(); done = true; }
        else {
          STEP(kfA, kfB, S1, S0);
          if (t + 1 >= cnt) { SOFTMAX(S0, dg); PVSTEP(); done = true; }
        }
      }
    }
#undef STEP
  }

  // ---- combine partials across the 4 waves ----
  if (wave != 0) {
    float* dst = &cbuf[wave - 1][lane][0];
    *(float4*)(dst +  0) = (float4){ot0[0],  ot0[1],  ot0[2],  ot0[3]};
    *(float4*)(dst +  4) = (float4){ot0[4],  ot0[5],  ot0[6],  ot0[7]};
    *(float4*)(dst +  8) = (float4){ot0[8],  ot0[9],  ot0[10], ot0[11]};
    *(float4*)(dst + 12) = (float4){ot0[12], ot0[13], ot0[14], ot0[15]};
    *(float4*)(dst + 16) = (float4){ot1[0],  ot1[1],  ot1[2],  ot1[3]};
    *(float4*)(dst + 20) = (float4){ot1[4],  ot1[5],  ot1[6],  ot1[7]};
    *(float4*)(dst + 24) = (float4){ot1[8],  ot1[9],  ot1[10], ot1[11]};
    *(float4*)(dst + 28) = (float4){ot1[12], ot1[13], ot1[14], ot1[15]};
    dst[32] = m; dst[33] = l;
  }
  __syncthreads();
  if (wave == 0) {
    float mw0 = cbuf[0][lane][32], lw0 = cbuf[0][lane][33];
    float mw1 = cbuf[1][lane][32], lw1 = cbuf[1][lane][33];
    float mw2 = cbuf[2][lane][32], lw2 = cbuf[2][lane][33];
    float M = fmaxf(fmaxf(m, mw0), fmaxf(mw1, mw2));
    float c = exp2f(m - M);
    l *= c;
    #pragma unroll
    for (int rr = 0; rr < 16; ++rr) { ot0[rr] *= c; ot1[rr] *= c; }
    #pragma unroll
    for (int w = 0; w < 3; ++w) {
      float mw = (w == 0) ? mw0 : (w == 1) ? mw1 : mw2;
      float lw = (w == 0) ? lw0 : (w == 1) ? lw1 : lw2;
      float cw = exp2f(mw - M);
      l += cw * lw;
      const float* src = &cbuf[w][lane][0];
      #pragma unroll
      for (int i = 0; i < 4; ++i) {
        float4 v0 = *(const float4*)(src + 4 * i);
        float4 v1 = *(const float4*)(src + 16 + 4 * i);
        ot0[4*i+0] += cw * v0.x; ot0[4*i+1] += cw * v0.y;
        ot0[4*i+2] += cw * v0.z; ot0[4*i+3] += cw * v0.w;
        ot1[4*i+0] += cw * v1.x; ot1[4*i+1] += cw * v1.y;
        ot1[4*i+2] += cw * v1.z; ot1[4*i+3] += cw * v1.w;
      }
    }
    float inv = 1.f / l;
    unsigned short* yrow = y + ((size_t)b * T_ + q0 + col) * C_ + h * D_;
    #pragma unroll
    for (int a = 0; a < 4; ++a) {
      ushort4 o4;
      o4.x = f2bf(ot0[4 * a + 0] * inv);
      o4.y = f2bf(ot0[4 * a + 1] * inv);
      o4.z = f2bf(ot0[4 * a + 2] * inv);
      o4.w = f2bf(ot0[4 * a + 3] * inv);
      *(ushort4*)(yrow + 8 * a + 4 * hi) = o4;
    }
    #pragma unroll
    for (int a = 0; a < 4; ++a) {
      ushort4 o4;
      o4.x = f2bf(ot1[4 * a + 0] * inv);
      o4.y = f2bf(ot1[4 * a + 1] * inv);
      o4.z = f2bf(ot1[4 * a + 2] * inv);
      o4.w = f2bf(ot1[4 * a + 3] * inv);
      *(ushort4*)(yrow + 32 + 8 * a + 4 * hi) = o4;
    }
  }
}

extern "C" void kernel_launch(void* const* d_in, const int* in_sizes, int n_in,
                              void* d_out, int out_size, void* d_ws, size_t ws_size,
                              hipStream_t stream) {
  const float* x  = (const float*)d_in[0];
  const float* Wq = (const float*)d_in[1];
  const float* bq = (const float*)d_in[2];
  const float* Wk = (const float*)d_in[3];
  const float* bk = (const float*)d_in[4];
  const float* Wv = (const float*)d_in[5];
  const float* bv = (const float*)d_in[6];
  const float* Wp = (const float*)d_in[7];
  const float* bp = (const float*)d_in[8];
  float* out = (float*)d_out;

  char* ws = (char*)d_ws;
  unsigned short* xb    = (unsigned short*)ws; ws += (size_t)M_ * C_ * 2;
  unsigned short* wqkvt = (unsigned short*)ws; ws += (size_t)3 * C_ * C_ * 2;
  unsigned short* wpt   = (unsigned short*)ws; ws += (size_t)C_ * C_ * 2;
  unsigned short* qb    = (unsigned short*)ws; ws += (size_t)M_ * C_ * 2;
  unsigned short* kb    = (unsigned short*)ws; ws += (size_t)M_ * C_ * 2;
  unsigned short* vtb   = (unsigned short*)ws; ws += (size_t)M_ * C_ * 2;
  unsigned short* yb    = (unsigned short*)ws; ws += (size_t)M_ * C_ * 2;

  cvt_f32_bf16<<<dim3((M_ * C_ / 4 + 255) / 256), dim3(256), 0, stream>>>(x, xb, M_ * C_ / 4);
  transpose_cvt<<<dim3(32, 32, 4), dim3(32, 8), 0, stream>>>(Wq, Wk, Wv, Wp, wqkvt, wpt);

  const float qscale = 0.125f * 1.4426950408889634f;  // 1/sqrt(64) * log2(e)
  gemm_qkv<<<dim3(3 * C_ / 128, M_ / 128), dim3(256), 0, stream>>>(
      xb, wqkvt, bq, bk, bv, qb, kb, vtb, qscale);

  attn8<<<dim3(4096), dim3(256), 0, stream>>>(qb, kb, vtb, yb);

  gemm_proj<<<dim3(C_ / 128, M_ / 128), dim3(256), 0, stream>>>(yb, wpt, bp, out);
}

// Round 10
// 241.006 us; speedup vs baseline: 1.6119x; 1.6119x over previous
//
#include <hip/hip_runtime.h>
#include <hip/hip_bf16.h>

#define B_ 4
#define T_ 2048
#define C_ 1024
#define H_ 16
#define D_ 64
#define M_ (B_*T_)   // 8192

typedef __bf16 bf16x8 __attribute__((ext_vector_type(8)));
typedef float  f32x4  __attribute__((ext_vector_type(4)));
typedef float  f32x16 __attribute__((ext_vector_type(16)));

__device__ __forceinline__ unsigned short f2bf(float f) {
  unsigned u = __builtin_bit_cast(unsigned, f);
  u += 0x7FFF + ((u >> 16) & 1);   // round-to-nearest-even
  return (unsigned short)(u >> 16);
}

__device__ __forceinline__ float exp2fast(float x) {
#if __has_builtin(__builtin_amdgcn_exp2f)
  return __builtin_amdgcn_exp2f(x);
#else
  float r; asm("v_exp_f32 %0, %1" : "=v"(r) : "v"(x)); return r;
#endif
}

__device__ __forceinline__ void gload_lds16(const void* g, void* l) {
  __builtin_amdgcn_global_load_lds(
      (const __attribute__((address_space(1))) void*)g,
      (__attribute__((address_space(3))) void*)l, 16, 0, 0);
}

// ---------------- conversion: f32 -> bf16 (vectorized) ----------------
__global__ void cvt_f32_bf16(const float* __restrict__ in,
                             unsigned short* __restrict__ out, int n4) {
  int i = blockIdx.x * blockDim.x + threadIdx.x;
  if (i < n4) {
    float4 v = ((const float4*)in)[i];
    ushort4 o;
    o.x = f2bf(v.x); o.y = f2bf(v.y); o.z = f2bf(v.z); o.w = f2bf(v.w);
    ((ushort4*)out)[i] = o;
  }
}

// ------------- weight transpose + convert: W[K][N] f32 -> Wt[N][K] bf16 -------------
__global__ void transpose_cvt(const float* __restrict__ w0, const float* __restrict__ w1,
                              const float* __restrict__ w2, const float* __restrict__ w3,
                              unsigned short* __restrict__ tqkv,
                              unsigned short* __restrict__ tp) {
  __shared__ float tile[32][33];
  const float* src; unsigned short* dst;
  switch (blockIdx.z) {
    case 0: src = w0; dst = tqkv; break;
    case 1: src = w1; dst = tqkv + (size_t)C_ * C_; break;
    case 2: src = w2; dst = tqkv + (size_t)2 * C_ * C_; break;
    default: src = w3; dst = tp; break;
  }
  int bx = blockIdx.x * 32;  // n base
  int by = blockIdx.y * 32;  // k base
  int tx = threadIdx.x, ty = threadIdx.y;
  #pragma unroll
  for (int j = 0; j < 4; ++j)
    tile[ty + 8*j][tx] = src[(size_t)(by + ty + 8*j) * C_ + bx + tx];
  __syncthreads();
  #pragma unroll
  for (int j = 0; j < 4; ++j)
    dst[(size_t)(bx + ty + 8*j) * C_ + by + tx] = f2bf(tile[tx][ty + 8*j]);
}

// ---------------- fused QKV GEMM: xb[M][K] @ wqkvt[3N][K]^T ----------------
__global__ __launch_bounds__(256, 2)
void gemm_qkv(const unsigned short* __restrict__ A,
              const unsigned short* __restrict__ Bt,
              const float* __restrict__ bq, const float* __restrict__ bk,
              const float* __restrict__ bv,
              unsigned short* __restrict__ qout, unsigned short* __restrict__ kout,
              unsigned short* __restrict__ vout, float qscale)
{
  __shared__ unsigned short lsA[128 * 64];
  __shared__ unsigned short lsB[128 * 64];
  const int wave = threadIdx.x >> 6;
  const int lane = threadIdx.x & 63;
  const int rowBase = blockIdx.y * 128;
  const int colBase = blockIdx.x * 128;
  const int rowOff = (wave >> 1) * 64;
  const int colOff = (wave & 1) * 64;
  const int lr = lane & 15;
  const int lg = lane >> 4;

  f32x4 acc[4][4] = {};

  const int chunkRow = lane >> 3;
  const int srcColE  = (((lane & 7) ^ (lane >> 3)) * 8);

  for (int k0 = 0; k0 < C_; k0 += 64) {
    #pragma unroll
    for (int c = 0; c < 4; ++c) {
      int chunk = c * 4 + wave;
      int r = chunk * 8 + chunkRow;
      gload_lds16(A  + (size_t)(rowBase + r) * C_ + k0 + srcColE, &lsA[chunk * 512]);
      gload_lds16(Bt + (size_t)(colBase + r) * C_ + k0 + srcColE, &lsB[chunk * 512]);
    }
    __syncthreads();
    #pragma unroll
    for (int kk = 0; kk < 2; ++kk) {
      bf16x8 af[4], bfr[4];
      const int kbyte = (kk * 32 + lg * 8) * 2;
      #pragma unroll
      for (int m = 0; m < 4; ++m) {
        int row = rowOff + m * 16 + lr;
        af[m] = *(const bf16x8*)((const char*)lsA + row * 128 + (kbyte ^ ((row & 7) << 4)));
      }
      #pragma unroll
      for (int n = 0; n < 4; ++n) {
        int row = colOff + n * 16 + lr;
        bfr[n] = *(const bf16x8*)((const char*)lsB + row * 128 + (kbyte ^ ((row & 7) << 4)));
      }
      #pragma unroll
      for (int m = 0; m < 4; ++m)
        #pragma unroll
        for (int n = 0; n < 4; ++n)
          acc[m][n] = __builtin_amdgcn_mfma_f32_16x16x32_bf16(af[m], bfr[n], acc[m][n], 0, 0, 0);
    }
    __syncthreads();
  }

  const int mid = colBase >> 10;                 // 0=Q 1=K 2=V (block-uniform)
  const float* bias = (mid == 0) ? bq : (mid == 1) ? bk : bv;
  const float oscale = (mid == 0) ? qscale : 1.f;
  unsigned short* outp = (mid == 0) ? qout : (mid == 1) ? kout : vout;

  #pragma unroll
  for (int m = 0; m < 4; ++m) {
    int row0 = rowBase + rowOff + m * 16 + lg * 4;
    #pragma unroll
    for (int n = 0; n < 4; ++n) {
      int col = colBase + colOff + n * 16 + lr;
      int ncol = col & 1023;
      float bs = bias[ncol];
      int h = ncol >> 6, d = ncol & 63;
      if (mid == 2) {
        int b = row0 >> 11, t = row0 & 2047;
        int t2 = (t & ~12) | ((t & 4) << 1) | ((t & 8) >> 1);  // key-perm (bits 2<->3)
        ushort4 o;
        o.x = f2bf(acc[m][n][0] + bs);
        o.y = f2bf(acc[m][n][1] + bs);
        o.z = f2bf(acc[m][n][2] + bs);
        o.w = f2bf(acc[m][n][3] + bs);
        *(ushort4*)(outp + (((size_t)b * H_ + h) * D_ + d) * T_ + t2) = o;
      } else {
        #pragma unroll
        for (int j = 0; j < 4; ++j) {
          int r = row0 + j;
          int b = r >> 11, t = r & 2047;
          outp[((((size_t)b * H_ + h) * T_ + t) << 6) + d] = f2bf((acc[m][n][j] + bs) * oscale);
        }
      }
    }
  }
}

// ---------------- final projection GEMM: yb[M][K] @ wpt[N][K]^T -> f32 ----------------
__global__ __launch_bounds__(256, 2)
void gemm_proj(const unsigned short* __restrict__ A,
               const unsigned short* __restrict__ Bt,
               const float* __restrict__ bias,
               float* __restrict__ Cout)
{
  __shared__ unsigned short lsA[128 * 64];
  __shared__ unsigned short lsB[128 * 64];
  const int wave = threadIdx.x >> 6;
  const int lane = threadIdx.x & 63;
  const int rowBase = blockIdx.y * 128;
  const int colBase = blockIdx.x * 128;
  const int rowOff = (wave >> 1) * 64;
  const int colOff = (wave & 1) * 64;
  const int lr = lane & 15;
  const int lg = lane >> 4;

  f32x4 acc[4][4] = {};

  const int chunkRow = lane >> 3;
  const int srcColE  = (((lane & 7) ^ (lane >> 3)) * 8);

  for (int k0 = 0; k0 < C_; k0 += 64) {
    #pragma unroll
    for (int c = 0; c < 4; ++c) {
      int chunk = c * 4 + wave;
      int r = chunk * 8 + chunkRow;
      gload_lds16(A  + (size_t)(rowBase + r) * C_ + k0 + srcColE, &lsA[chunk * 512]);
      gload_lds16(Bt + (size_t)(colBase + r) * C_ + k0 + srcColE, &lsB[chunk * 512]);
    }
    __syncthreads();
    #pragma unroll
    for (int kk = 0; kk < 2; ++kk) {
      bf16x8 af[4], bfr[4];
      const int kbyte = (kk * 32 + lg * 8) * 2;
      #pragma unroll
      for (int m = 0; m < 4; ++m) {
        int row = rowOff + m * 16 + lr;
        af[m] = *(const bf16x8*)((const char*)lsA + row * 128 + (kbyte ^ ((row & 7) << 4)));
      }
      #pragma unroll
      for (int n = 0; n < 4; ++n) {
        int row = colOff + n * 16 + lr;
        bfr[n] = *(const bf16x8*)((const char*)lsB + row * 128 + (kbyte ^ ((row & 7) << 4)));
      }
      #pragma unroll
      for (int m = 0; m < 4; ++m)
        #pragma unroll
        for (int n = 0; n < 4; ++n)
          acc[m][n] = __builtin_amdgcn_mfma_f32_16x16x32_bf16(af[m], bfr[n], acc[m][n], 0, 0, 0);
    }
    __syncthreads();
  }

  #pragma unroll
  for (int m = 0; m < 4; ++m) {
    int row0 = rowBase + rowOff + m * 16 + lg * 4;
    #pragma unroll
    for (int n = 0; n < 4; ++n) {
      int col = colBase + colOff + n * 16 + lr;
      float bs = bias[col];
      #pragma unroll
      for (int j = 0; j < 4; ++j)
        Cout[(size_t)(row0 + j) * C_ + col] = acc[m][n][j] + bs;
    }
  }
}

// ---------------- causal flash attention: latency-cut softmax ----------------
// q,k: [B][H][T][D] bf16 (q pre-scaled by log2e/sqrt(D)); vp: [B][H][D][T] bf16 key-permuted
// (bits 2<->3 of t swapped) so global layout == MFMA A-fragment layout; y: [B][T][C] bf16.
// One wave per 32-row q-tile, 4096 waves (1024 blocks x 4), longest-first, XCD-local heads.
// Common path per tile: QK^T 4-chain -> local (half-row) max tree -> lane-local defer-max
// check -> raw v_exp_f32 -> PV. Cross-lane exchange (__shfl_xor 32) only on the rare
// rescale path and once in the epilogue. l kept half-lane-local.
__global__ __launch_bounds__(256, 3)
void attn10(const unsigned short* __restrict__ q,
            const unsigned short* __restrict__ k,
            const unsigned short* __restrict__ vp,
            unsigned short* __restrict__ y)
{
  const int wave = threadIdx.x >> 6;
  const int lane = threadIdx.x & 63;
  const int col  = lane & 31;   // query index within 32 (and K-row / V-d-row index)
  const int hi   = lane >> 5;

  // decode: 1024 blocks; xcd-local heads; longest q-tiles first
  const int bid = blockIdx.x;            // 0..1023
  const int xcd = bid & 7;
  const int idx = bid >> 3;              // 0..127
  const int bh  = xcd * 8 + (idx & 7);   // 8 heads per XCD
  const int g   = idx >> 3;              // 0..15
  const int qt  = 63 - (g * 4 + wave);   // 63..0, longest first
  const int q0  = qt * 32;
  const int ntiles = qt + 1;
  const int b = bh >> 4, h = bh & 15;

  const unsigned short* qh = q  + (size_t)bh * T_ * D_;
  const unsigned short* kh = k  + (size_t)bh * T_ * D_;
  const unsigned short* vh = vp + (size_t)bh * D_ * T_;

  // Q B-fragments: bqf[ks] = Q[q0+col][ks*16 + hi*8 + e]
  bf16x8 bqf[4];
  {
    const unsigned short* qrow = qh + (size_t)(q0 + col) * D_ + hi * 8;
    #pragma unroll
    for (int ks = 0; ks < 4; ++ks) bqf[ks] = *(const bf16x8*)(qrow + ks * 16);
  }

  f32x16 ot0 = {}, ot1 = {};
  float m = -INFINITY, l = 0.f;     // l is HALF-LOCAL (this lane's 16 key-slots per tile)
  const f32x16 zc = {};

  bf16x8 kfA[4], kfB[4], vf[4];
  f32x16 S0, S1;
  bf16x8 pf0, pf1;

  const unsigned short* kbase = kh + (size_t)col * D_ + hi * 8;
  const unsigned short* vbase = vh + (size_t)col * T_ + hi * 8;
  const unsigned short* kld = kbase + 2 * 32 * D_;   // next K load: tile 2
  const unsigned short* vld = vbase + 32;            // next V load: tile 1

  // prologue: K0, V0, K1; S0 = QK^T(tile 0)
  #pragma unroll
  for (int ks = 0; ks < 4; ++ks) kfA[ks] = *(const bf16x8*)(kbase + ks * 16);
  #pragma unroll
  for (int dt = 0; dt < 2; ++dt)
    #pragma unroll
    for (int ks = 0; ks < 2; ++ks)
      vf[dt * 2 + ks] = *(const bf16x8*)(vbase + dt * 32 * T_ + ks * 16);
  if (ntiles > 1) {
    #pragma unroll
    for (int ks = 0; ks < 4; ++ks) kfB[ks] = *(const bf16x8*)(kbase + 32 * D_ + ks * 16);
  }
  S0 = __builtin_amdgcn_mfma_f32_32x32x16_bf16(kfA[0], bqf[0], zc, 0, 0, 0);
  S0 = __builtin_amdgcn_mfma_f32_32x32x16_bf16(kfA[1], bqf[1], S0, 0, 0, 0);
  S0 = __builtin_amdgcn_mfma_f32_32x32x16_bf16(kfA[2], bqf[2], S0, 0, 0, 0);
  S0 = __builtin_amdgcn_mfma_f32_32x32x16_bf16(kfA[3], bqf[3], S0, 0, 0, 0);

  int t = 0;

  auto SOFTMAX = [&](f32x16& S, bool diag) {
    if (diag) {
      #pragma unroll
      for (int rr = 0; rr < 16; ++rr) {
        int key = t * 32 + (rr & 3) + 8 * (rr >> 2) + 4 * hi;
        if (key > q0 + col) S[rr] = -INFINITY;
      }
    }
    float a0 = fmaxf(fmaxf(S[0], S[1]), fmaxf(S[2], S[3]));
    float a1 = fmaxf(fmaxf(S[4], S[5]), fmaxf(S[6], S[7]));
    float a2 = fmaxf(fmaxf(S[8], S[9]), fmaxf(S[10], S[11]));
    float a3 = fmaxf(fmaxf(S[12], S[13]), fmaxf(S[14], S[15]));
    float mm = fmaxf(fmaxf(a0, a1), fmaxf(a2, a3));     // local (half-row) max only
    if (!__all(mm <= m + 8.f)) {                        // rare path: update shared m
      float mf = fmaxf(mm, __shfl_xor(mm, 32));         // full-row max
      float mnew = fmaxf(m, mf);
      float corr = exp2fast(m - mnew);
      m = mnew;
      l *= corr;
      #pragma unroll
      for (int rr = 0; rr < 16; ++rr) { ot0[rr] *= corr; ot1[rr] *= corr; }
    }
    {
      float pa[8];
      bf16x8 w;
      #pragma unroll
      for (int e = 0; e < 8; ++e) { pa[e] = exp2fast(S[e] - m); w[e] = (__bf16)pa[e]; }
      pf0 = w;
      l += ((pa[0] + pa[1]) + (pa[2] + pa[3])) + ((pa[4] + pa[5]) + (pa[6] + pa[7]));
    }
    {
      float pb[8];
      bf16x8 w;
      #pragma unroll
      for (int e = 0; e < 8; ++e) { pb[e] = exp2fast(S[8 + e] - m); w[e] = (__bf16)pb[e]; }
      pf1 = w;
      l += ((pb[0] + pb[1]) + (pb[2] + pb[3])) + ((pb[4] + pb[5]) + (pb[6] + pb[7]));
    }
  };

  auto PVSTEP = [&]() {
    __builtin_amdgcn_s_setprio(1);
    ot0 = __builtin_amdgcn_mfma_f32_32x32x16_bf16(vf[0], pf0, ot0, 0, 0, 0);
    ot1 = __builtin_amdgcn_mfma_f32_32x32x16_bf16(vf[2], pf0, ot1, 0, 0, 0);
    ot0 = __builtin_amdgcn_mfma_f32_32x32x16_bf16(vf[1], pf1, ot0, 0, 0, 0);
    ot1 = __builtin_amdgcn_mfma_f32_32x32x16_bf16(vf[3], pf1, ot1, 0, 0, 0);
    __builtin_amdgcn_s_setprio(0);
  };

#define STEP(KN, KL, SCUR, SNEW)                                                    \
  do {                                                                              \
    __builtin_amdgcn_s_setprio(1);                                                  \
    SNEW = __builtin_amdgcn_mfma_f32_32x32x16_bf16(KN[0], bqf[0], zc,   0, 0, 0);   \
    SNEW = __builtin_amdgcn_mfma_f32_32x32x16_bf16(KN[1], bqf[1], SNEW, 0, 0, 0);   \
    SNEW = __builtin_amdgcn_mfma_f32_32x32x16_bf16(KN[2], bqf[2], SNEW, 0, 0, 0);   \
    SNEW = __builtin_amdgcn_mfma_f32_32x32x16_bf16(KN[3], bqf[3], SNEW, 0, 0, 0);   \
    __builtin_amdgcn_s_setprio(0);                                                  \
    if (t + 2 < ntiles) {                                                           \
      _Pragma("unroll")                                                             \
      for (int ks = 0; ks < 4; ++ks) KL[ks] = *(const bf16x8*)(kld + ks * 16);      \
      kld += 32 * D_;                                                               \
    }                                                                               \
    SOFTMAX(SCUR, false);                                                           \
    PVSTEP();                                                                       \
    _Pragma("unroll")                                                               \
    for (int dt = 0; dt < 2; ++dt) {                                                \
      _Pragma("unroll")                                                             \
      for (int ks = 0; ks < 2; ++ks)                                                \
        vf[dt * 2 + ks] = *(const bf16x8*)(vld + dt * 32 * T_ + ks * 16);           \
    }                                                                               \
    vld += 32;                                                                      \
    ++t;                                                                            \
  } while (0)

  if (ntiles == 1) {
    SOFTMAX(S0, true);
    PVSTEP();
  } else {
    bool done = false;
    while (!done) {
      STEP(kfB, kfA, S0, S1);
      if (t + 1 >= ntiles) { SOFTMAX(S1, true); PVSTEP(); done = true; }
      else {
        STEP(kfA, kfB, S1, S0);
        if (t + 1 >= ntiles) { SOFTMAX(S0, true); PVSTEP(); done = true; }
      }
    }
  }
#undef STEP

  // ---- combine half-local l, normalize, store y[B][T][C] ----
  float lf = l + __shfl_xor(l, 32);
  float inv = 1.f / lf;
  unsigned short* yrow = y + ((size_t)b * T_ + q0 + col) * C_ + h * D_;
  #pragma unroll
  for (int a = 0; a < 4; ++a) {
    ushort4 o4;
    o4.x = f2bf(ot0[4 * a + 0] * inv);
    o4.y = f2bf(ot0[4 * a + 1] * inv);
    o4.z = f2bf(ot0[4 * a + 2] * inv);
    o4.w = f2bf(ot0[4 * a + 3] * inv);
    *(ushort4*)(yrow + 8 * a + 4 * hi) = o4;
  }
  #pragma unroll
  for (int a = 0; a < 4; ++a) {
    ushort4 o4;
    o4.x = f2bf(ot1[4 * a + 0] * inv);
    o4.y = f2bf(ot1[4 * a + 1] * inv);
    o4.z = f2bf(ot1[4 * a + 2] * inv);
    o4.w = f2bf(ot1[4 * a + 3] * inv);
    *(ushort4*)(yrow + 32 + 8 * a + 4 * hi) = o4;
  }
}

extern "C" void kernel_launch(void* const* d_in, const int* in_sizes, int n_in,
                              void* d_out, int out_size, void* d_ws, size_t ws_size,
                              hipStream_t stream) {
  const float* x  = (const float*)d_in[0];
  const float* Wq = (const float*)d_in[1];
  const float* bq = (const float*)d_in[2];
  const float* Wk = (const float*)d_in[3];
  const float* bk = (const float*)d_in[4];
  const float* Wv = (const float*)d_in[5];
  const float* bv = (const float*)d_in[6];
  const float* Wp = (const float*)d_in[7];
  const float* bp = (const float*)d_in[8];
  float* out = (float*)d_out;

  char* ws = (char*)d_ws;
  unsigned short* xb    = (unsigned short*)ws; ws += (size_t)M_ * C_ * 2;
  unsigned short* wqkvt = (unsigned short*)ws; ws += (size_t)3 * C_ * C_ * 2;
  unsigned short* wpt   = (unsigned short*)ws; ws += (size_t)C_ * C_ * 2;
  unsigned short* qb    = (unsigned short*)ws; ws += (size_t)M_ * C_ * 2;
  unsigned short* kb    = (unsigned short*)ws; ws += (size_t)M_ * C_ * 2;
  unsigned short* vtb   = (unsigned short*)ws; ws += (size_t)M_ * C_ * 2;
  unsigned short* yb    = (unsigned short*)ws; ws += (size_t)M_ * C_ * 2;

  cvt_f32_bf16<<<dim3((M_ * C_ / 4 + 255) / 256), dim3(256), 0, stream>>>(x, xb, M_ * C_ / 4);
  transpose_cvt<<<dim3(32, 32, 4), dim3(32, 8), 0, stream>>>(Wq, Wk, Wv, Wp, wqkvt, wpt);

  const float qscale = 0.125f * 1.4426950408889634f;  // 1/sqrt(64) * log2(e)
  gemm_qkv<<<dim3(3 * C_ / 128, M_ / 128), dim3(256), 0, stream>>>(
      xb, wqkvt, bq, bk, bv, qb, kb, vtb, qscale);

  attn10<<<dim3(1024), dim3(256), 0, stream>>>(qb, kb, vtb, yb);

  gemm_proj<<<dim3(C_ / 128, M_ / 128), dim3(256), 0, stream>>>(yb, wpt, bp, out);
}

// Round 11
// 166.434 us; speedup vs baseline: 2.3341x; 1.4481x over previous
//
#include <hip/hip_runtime.h>
#include <hip/hip_bf16.h>

#define B_ 4
#define T_ 2048
#define C_ 1024
#define H_ 16
#define D_ 64
#define M_ (B_*T_)   // 8192

typedef __bf16 bf16x8 __attribute__((ext_vector_type(8)));
typedef float  f32x4  __attribute__((ext_vector_type(4)));
typedef float  f32x16 __attribute__((ext_vector_type(16)));

__device__ __forceinline__ unsigned short f2bf(float f) {
  unsigned u = __builtin_bit_cast(unsigned, f);
  u += 0x7FFF + ((u >> 16) & 1);   // round-to-nearest-even
  return (unsigned short)(u >> 16);
}

__device__ __forceinline__ float exp2fast(float x) {
#if __has_builtin(__builtin_amdgcn_exp2f)
  return __builtin_amdgcn_exp2f(x);
#else
  float r; asm("v_exp_f32 %0, %1" : "=v"(r) : "v"(x)); return r;
#endif
}

__device__ __forceinline__ void gload_lds16(const void* g, void* l) {
  __builtin_amdgcn_global_load_lds(
      (const __attribute__((address_space(1))) void*)g,
      (__attribute__((address_space(3))) void*)l, 16, 0, 0);
}

// ---------------- conversion: f32 -> bf16 (vectorized) ----------------
__global__ void cvt_f32_bf16(const float* __restrict__ in,
                             unsigned short* __restrict__ out, int n4) {
  int i = blockIdx.x * blockDim.x + threadIdx.x;
  if (i < n4) {
    float4 v = ((const float4*)in)[i];
    ushort4 o;
    o.x = f2bf(v.x); o.y = f2bf(v.y); o.z = f2bf(v.z); o.w = f2bf(v.w);
    ((ushort4*)out)[i] = o;
  }
}

// ------------- weight transpose + convert: W[K][N] f32 -> Wt[N][K] bf16 -------------
__global__ void transpose_cvt(const float* __restrict__ w0, const float* __restrict__ w1,
                              const float* __restrict__ w2, const float* __restrict__ w3,
                              unsigned short* __restrict__ tqkv,
                              unsigned short* __restrict__ tp) {
  __shared__ float tile[32][33];
  const float* src; unsigned short* dst;
  switch (blockIdx.z) {
    case 0: src = w0; dst = tqkv; break;
    case 1: src = w1; dst = tqkv + (size_t)C_ * C_; break;
    case 2: src = w2; dst = tqkv + (size_t)2 * C_ * C_; break;
    default: src = w3; dst = tp; break;
  }
  int bx = blockIdx.x * 32;  // n base
  int by = blockIdx.y * 32;  // k base
  int tx = threadIdx.x, ty = threadIdx.y;
  #pragma unroll
  for (int j = 0; j < 4; ++j)
    tile[ty + 8*j][tx] = src[(size_t)(by + ty + 8*j) * C_ + bx + tx];
  __syncthreads();
  #pragma unroll
  for (int j = 0; j < 4; ++j)
    dst[(size_t)(bx + ty + 8*j) * C_ + by + tx] = f2bf(tile[tx][ty + 8*j]);
}

// ---------------- fused QKV GEMM: xb[M][K] @ wqkvt[3N][K]^T ----------------
__global__ __launch_bounds__(256, 2)
void gemm_qkv(const unsigned short* __restrict__ A,
              const unsigned short* __restrict__ Bt,
              const float* __restrict__ bq, const float* __restrict__ bk,
              const float* __restrict__ bv,
              unsigned short* __restrict__ qout, unsigned short* __restrict__ kout,
              unsigned short* __restrict__ vout, float qscale)
{
  __shared__ unsigned short lsA[128 * 64];
  __shared__ unsigned short lsB[128 * 64];
  const int wave = threadIdx.x >> 6;
  const int lane = threadIdx.x & 63;
  const int rowBase = blockIdx.y * 128;
  const int colBase = blockIdx.x * 128;
  const int rowOff = (wave >> 1) * 64;
  const int colOff = (wave & 1) * 64;
  const int lr = lane & 15;
  const int lg = lane >> 4;

  f32x4 acc[4][4] = {};

  const int chunkRow = lane >> 3;
  const int srcColE  = (((lane & 7) ^ (lane >> 3)) * 8);

  for (int k0 = 0; k0 < C_; k0 += 64) {
    #pragma unroll
    for (int c = 0; c < 4; ++c) {
      int chunk = c * 4 + wave;
      int r = chunk * 8 + chunkRow;
      gload_lds16(A  + (size_t)(rowBase + r) * C_ + k0 + srcColE, &lsA[chunk * 512]);
      gload_lds16(Bt + (size_t)(colBase + r) * C_ + k0 + srcColE, &lsB[chunk * 512]);
    }
    __syncthreads();
    #pragma unroll
    for (int kk = 0; kk < 2; ++kk) {
      bf16x8 af[4], bfr[4];
      const int kbyte = (kk * 32 + lg * 8) * 2;
      #pragma unroll
      for (int m = 0; m < 4; ++m) {
        int row = rowOff + m * 16 + lr;
        af[m] = *(const bf16x8*)((const char*)lsA + row * 128 + (kbyte ^ ((row & 7) << 4)));
      }
      #pragma unroll
      for (int n = 0; n < 4; ++n) {
        int row = colOff + n * 16 + lr;
        bfr[n] = *(const bf16x8*)((const char*)lsB + row * 128 + (kbyte ^ ((row & 7) << 4)));
      }
      #pragma unroll
      for (int m = 0; m < 4; ++m)
        #pragma unroll
        for (int n = 0; n < 4; ++n)
          acc[m][n] = __builtin_amdgcn_mfma_f32_16x16x32_bf16(af[m], bfr[n], acc[m][n], 0, 0, 0);
    }
    __syncthreads();
  }

  const int mid = colBase >> 10;                 // 0=Q 1=K 2=V (block-uniform)
  const float* bias = (mid == 0) ? bq : (mid == 1) ? bk : bv;
  const float oscale = (mid == 0) ? qscale : 1.f;
  unsigned short* outp = (mid == 0) ? qout : (mid == 1) ? kout : vout;

  #pragma unroll
  for (int m = 0; m < 4; ++m) {
    int row0 = rowBase + rowOff + m * 16 + lg * 4;
    #pragma unroll
    for (int n = 0; n < 4; ++n) {
      int col = colBase + colOff + n * 16 + lr;
      int ncol = col & 1023;
      float bs = bias[ncol];
      int h = ncol >> 6, d = ncol & 63;
      if (mid == 2) {
        int b = row0 >> 11, t = row0 & 2047;
        int t2 = (t & ~12) | ((t & 4) << 1) | ((t & 8) >> 1);  // key-perm (bits 2<->3)
        ushort4 o;
        o.x = f2bf(acc[m][n][0] + bs);
        o.y = f2bf(acc[m][n][1] + bs);
        o.z = f2bf(acc[m][n][2] + bs);
        o.w = f2bf(acc[m][n][3] + bs);
        *(ushort4*)(outp + (((size_t)b * H_ + h) * D_ + d) * T_ + t2) = o;
      } else {
        #pragma unroll
        for (int j = 0; j < 4; ++j) {
          int r = row0 + j;
          int b = r >> 11, t = r & 2047;
          outp[((((size_t)b * H_ + h) * T_ + t) << 6) + d] = f2bf((acc[m][n][j] + bs) * oscale);
        }
      }
    }
  }
}

// ---------------- final projection GEMM: yb[M][K] @ wpt[N][K]^T -> f32 ----------------
__global__ __launch_bounds__(256, 2)
void gemm_proj(const unsigned short* __restrict__ A,
               const unsigned short* __restrict__ Bt,
               const float* __restrict__ bias,
               float* __restrict__ Cout)
{
  __shared__ unsigned short lsA[128 * 64];
  __shared__ unsigned short lsB[128 * 64];
  const int wave = threadIdx.x >> 6;
  const int lane = threadIdx.x & 63;
  const int rowBase = blockIdx.y * 128;
  const int colBase = blockIdx.x * 128;
  const int rowOff = (wave >> 1) * 64;
  const int colOff = (wave & 1) * 64;
  const int lr = lane & 15;
  const int lg = lane >> 4;

  f32x4 acc[4][4] = {};

  const int chunkRow = lane >> 3;
  const int srcColE  = (((lane & 7) ^ (lane >> 3)) * 8);

  for (int k0 = 0; k0 < C_; k0 += 64) {
    #pragma unroll
    for (int c = 0; c < 4; ++c) {
      int chunk = c * 4 + wave;
      int r = chunk * 8 + chunkRow;
      gload_lds16(A  + (size_t)(rowBase + r) * C_ + k0 + srcColE, &lsA[chunk * 512]);
      gload_lds16(Bt + (size_t)(colBase + r) * C_ + k0 + srcColE, &lsB[chunk * 512]);
    }
    __syncthreads();
    #pragma unroll
    for (int kk = 0; kk < 2; ++kk) {
      bf16x8 af[4], bfr[4];
      const int kbyte = (kk * 32 + lg * 8) * 2;
      #pragma unroll
      for (int m = 0; m < 4; ++m) {
        int row = rowOff + m * 16 + lr;
        af[m] = *(const bf16x8*)((const char*)lsA + row * 128 + (kbyte ^ ((row & 7) << 4)));
      }
      #pragma unroll
      for (int n = 0; n < 4; ++n) {
        int row = colOff + n * 16 + lr;
        bfr[n] = *(const bf16x8*)((const char*)lsB + row * 128 + (kbyte ^ ((row & 7) << 4)));
      }
      #pragma unroll
      for (int m = 0; m < 4; ++m)
        #pragma unroll
        for (int n = 0; n < 4; ++n)
          acc[m][n] = __builtin_amdgcn_mfma_f32_16x16x32_bf16(af[m], bfr[n], acc[m][n], 0, 0, 0);
    }
    __syncthreads();
  }

  #pragma unroll
  for (int m = 0; m < 4; ++m) {
    int row0 = rowBase + rowOff + m * 16 + lg * 4;
    #pragma unroll
    for (int n = 0; n < 4; ++n) {
      int col = colBase + colOff + n * 16 + lr;
      float bs = bias[col];
      #pragma unroll
      for (int j = 0; j < 4; ++j)
        Cout[(size_t)(row0 + j) * C_ + col] = acc[m][n][j] + bs;
    }
  }
}

// -------- causal flash attention: LDS-staged, triple-buffer, counted vmcnt, balanced ----
// q,k: [B][H][T][D] bf16 (q pre-scaled by log2e/sqrt(D)); vp: [B][H][D][T] bf16 key-permuted
// (bits 2<->3 of t swapped); y: [B][T][C] bf16.
// 512 blocks x 4 waves. Block = head + supertile-pair (p, 15-p): exactly 34 steps of 64
// keys -> perfectly uniform. K/V staged to LDS via global_load_lds (3 buffers, 48 KB),
// 2 stages in flight across raw s_barrier with counted s_waitcnt vmcnt(4) (T3/T4).
// Softmax: lane-local common path, exp2 via v_exp_f32, defer-max THR=8, half-local l.
__global__ __launch_bounds__(256, 2)
void attn11(const unsigned short* __restrict__ q,
            const unsigned short* __restrict__ k,
            const unsigned short* __restrict__ vp,
            unsigned short* __restrict__ y)
{
  __shared__ unsigned short lsK[3][64 * 64];   // 24 KB
  __shared__ unsigned short lsV[3][64 * 64];   // 24 KB
  const int tid  = threadIdx.x;
  const int wave = tid >> 6;
  const int lane = tid & 63;
  const int col  = lane & 31;
  const int hi   = lane >> 5;

  const int bid = blockIdx.x;            // 0..511
  const int xcd = bid & 7;
  const int idx = bid >> 3;              // 0..63
  const int bh  = xcd * 8 + (idx & 7);   // 8 heads per XCD
  const int pair = idx >> 3;             // 0..7
  const int b = bh >> 4, h = bh & 15;

  const unsigned short* qh = q  + (size_t)bh * T_ * D_;
  const unsigned short* kh = k  + (size_t)bh * T_ * D_;
  const unsigned short* vh = vp + (size_t)bh * D_ * T_;

  // staging source (inverse-swizzled): thread t -> LDS linear 16B chunks t and t+256
  const int srow = tid >> 3;                             // 0..31
  const int srcE = ((tid & 7) * 8) ^ ((srow & 7) << 3);
  const unsigned short* ksrc = kh + srow * D_ + srcE;
  const unsigned short* vsrc = vh + srow * T_ + srcE;

  const int swz = (col & 7) << 4;
  const f32x16 zc = {};

  #pragma unroll 1
  for (int phx = 0; phx < 2; ++phx) {
    const int qs = phx ? (15 - pair) : pair;   // supertile 0..15 (128 rows)
    const int q0 = qs * 128 + wave * 32;
    const int nsteps = 2 * qs + 2;

    // Q fragments
    bf16x8 bqf[4];
    {
      const unsigned short* qrow = qh + (size_t)(q0 + col) * D_ + hi * 8;
      #pragma unroll
      for (int ks = 0; ks < 4; ++ks) bqf[ks] = *(const bf16x8*)(qrow + ks * 16);
    }

    f32x16 ot0 = {}, ot1 = {};
    float m = -INFINITY, l = 0.f;
    bf16x8 pf0, pf1, pf2, pf3;

    // ensure all waves finished reading buffers (phase transition) before re-staging
    __builtin_amdgcn_s_barrier();
    __builtin_amdgcn_sched_barrier(0);

    auto STAGE = [&](int t) {
      unsigned short* bK = &lsK[0][0] + (t % 3) * 4096;
      unsigned short* bV = &lsV[0][0] + (t % 3) * 4096;
      const unsigned short* kg = ksrc + (size_t)t * 64 * D_;
      const unsigned short* vg = vsrc + t * 64;
      gload_lds16(kg,           bK + tid * 8);
      gload_lds16(kg + 32 * D_, bK + (tid + 256) * 8);
      gload_lds16(vg,           bV + tid * 8);
      gload_lds16(vg + 32 * T_, bV + (tid + 256) * 8);
    };

    STAGE(0);
    STAGE(1);

    for (int s = 0; s < nsteps; ++s) {
      if (s + 1 < nsteps) {
        asm volatile("s_waitcnt vmcnt(4)" ::: "memory");   // tile s landed (mine)
      } else {
        asm volatile("s_waitcnt vmcnt(0)" ::: "memory");   // last tile: drain
      }
      __builtin_amdgcn_s_barrier();                         // everyone's tile s landed
      __builtin_amdgcn_sched_barrier(0);
      if (s + 2 < nsteps) STAGE(s + 2);                     // 2-deep prefetch

      const int n0 = s * 64;
      if (n0 <= q0 + 31) {
        const bool two = (n0 < q0);
        const unsigned short* baseK = &lsK[0][0] + (s % 3) * 4096;
        const unsigned short* baseV = &lsV[0][0] + (s % 3) * 4096;
        // ---- QK^T ----
        f32x16 st0, st1;
        {
          const char* kb0 = (const char*)baseK + col * 128;
          __builtin_amdgcn_s_setprio(1);
          st0 = __builtin_amdgcn_mfma_f32_32x32x16_bf16(
                  *(const bf16x8*)(kb0 + ((0 * 32 + hi * 16) ^ swz)), bqf[0], zc, 0, 0, 0);
          st0 = __builtin_amdgcn_mfma_f32_32x32x16_bf16(
                  *(const bf16x8*)(kb0 + ((1 * 32 + hi * 16) ^ swz)), bqf[1], st0, 0, 0, 0);
          st0 = __builtin_amdgcn_mfma_f32_32x32x16_bf16(
                  *(const bf16x8*)(kb0 + ((2 * 32 + hi * 16) ^ swz)), bqf[2], st0, 0, 0, 0);
          st0 = __builtin_amdgcn_mfma_f32_32x32x16_bf16(
                  *(const bf16x8*)(kb0 + ((3 * 32 + hi * 16) ^ swz)), bqf[3], st0, 0, 0, 0);
          if (two) {
            const char* kb1 = kb0 + 32 * 128;
            f32x16 a;
            a = __builtin_amdgcn_mfma_f32_32x32x16_bf16(
                  *(const bf16x8*)(kb1 + ((0 * 32 + hi * 16) ^ swz)), bqf[0], zc, 0, 0, 0);
            a = __builtin_amdgcn_mfma_f32_32x32x16_bf16(
                  *(const bf16x8*)(kb1 + ((1 * 32 + hi * 16) ^ swz)), bqf[1], a, 0, 0, 0);
            a = __builtin_amdgcn_mfma_f32_32x32x16_bf16(
                  *(const bf16x8*)(kb1 + ((2 * 32 + hi * 16) ^ swz)), bqf[2], a, 0, 0, 0);
            a = __builtin_amdgcn_mfma_f32_32x32x16_bf16(
                  *(const bf16x8*)(kb1 + ((3 * 32 + hi * 16) ^ swz)), bqf[3], a, 0, 0, 0);
            st1 = a;
          }
          __builtin_amdgcn_s_setprio(0);
        }
        // ---- causal mask (diagonal region only) ----
        if (n0 + 63 > q0) {
          #pragma unroll
          for (int rr = 0; rr < 16; ++rr) {
            int key0 = n0 + (rr & 3) + 8 * (rr >> 2) + 4 * hi;
            if (key0 > q0 + col) st0[rr] = -INFINITY;
            if (two) { if (key0 + 32 > q0 + col) st1[rr] = -INFINITY; }
          }
        }
        // ---- softmax (lane-local common path) ----
        float mm;
        {
          float a0 = fmaxf(fmaxf(st0[0], st0[1]), fmaxf(st0[2], st0[3]));
          float a1 = fmaxf(fmaxf(st0[4], st0[5]), fmaxf(st0[6], st0[7]));
          float a2 = fmaxf(fmaxf(st0[8], st0[9]), fmaxf(st0[10], st0[11]));
          float a3 = fmaxf(fmaxf(st0[12], st0[13]), fmaxf(st0[14], st0[15]));
          if (two) {
            a0 = fmaxf(a0, fmaxf(fmaxf(st1[0], st1[1]), fmaxf(st1[2], st1[3])));
            a1 = fmaxf(a1, fmaxf(fmaxf(st1[4], st1[5]), fmaxf(st1[6], st1[7])));
            a2 = fmaxf(a2, fmaxf(fmaxf(st1[8], st1[9]), fmaxf(st1[10], st1[11])));
            a3 = fmaxf(a3, fmaxf(fmaxf(st1[12], st1[13]), fmaxf(st1[14], st1[15])));
          }
          mm = fmaxf(fmaxf(a0, a1), fmaxf(a2, a3));
        }
        if (!__all(mm <= m + 8.f)) {           // rare rescale path
          float mf = fmaxf(mm, __shfl_xor(mm, 32));
          float mnew = fmaxf(m, mf);
          float corr = exp2fast(m - mnew);
          m = mnew;
          l *= corr;
          #pragma unroll
          for (int rr = 0; rr < 16; ++rr) { ot0[rr] *= corr; ot1[rr] *= corr; }
        }
        {
          float pa[8];
          bf16x8 w;
          #pragma unroll
          for (int e = 0; e < 8; ++e) { pa[e] = exp2fast(st0[e] - m); w[e] = (__bf16)pa[e]; }
          pf0 = w;
          l += ((pa[0] + pa[1]) + (pa[2] + pa[3])) + ((pa[4] + pa[5]) + (pa[6] + pa[7]));
        }
        {
          float pb[8];
          bf16x8 w;
          #pragma unroll
          for (int e = 0; e < 8; ++e) { pb[e] = exp2fast(st0[8 + e] - m); w[e] = (__bf16)pb[e]; }
          pf1 = w;
          l += ((pb[0] + pb[1]) + (pb[2] + pb[3])) + ((pb[4] + pb[5]) + (pb[6] + pb[7]));
        }
        if (two) {
          float pa[8];
          bf16x8 w;
          #pragma unroll
          for (int e = 0; e < 8; ++e) { pa[e] = exp2fast(st1[e] - m); w[e] = (__bf16)pa[e]; }
          pf2 = w;
          l += ((pa[0] + pa[1]) + (pa[2] + pa[3])) + ((pa[4] + pa[5]) + (pa[6] + pa[7]));
          float pb[8];
          #pragma unroll
          for (int e = 0; e < 8; ++e) { pb[e] = exp2fast(st1[8 + e] - m); w[e] = (__bf16)pb[e]; }
          pf3 = w;
          l += ((pb[0] + pb[1]) + (pb[2] + pb[3])) + ((pb[4] + pb[5]) + (pb[6] + pb[7]));
        }
        // ---- PV ----
        {
          const char* vb0 = (const char*)baseV + col * 128;
          const char* vb1 = vb0 + 32 * 128;
          __builtin_amdgcn_s_setprio(1);
          #pragma unroll
          for (int ks = 0; ks < 2; ++ks) {
            bf16x8 pw = ks ? pf1 : pf0;
            bf16x8 av0 = *(const bf16x8*)(vb0 + ((ks * 32 + hi * 16) ^ swz));
            bf16x8 av1 = *(const bf16x8*)(vb1 + ((ks * 32 + hi * 16) ^ swz));
            ot0 = __builtin_amdgcn_mfma_f32_32x32x16_bf16(av0, pw, ot0, 0, 0, 0);
            ot1 = __builtin_amdgcn_mfma_f32_32x32x16_bf16(av1, pw, ot1, 0, 0, 0);
          }
          if (two) {
            #pragma unroll
            for (int ks = 2; ks < 4; ++ks) {
              bf16x8 pw = (ks == 3) ? pf3 : pf2;
              bf16x8 av0 = *(const bf16x8*)(vb0 + ((ks * 32 + hi * 16) ^ swz));
              bf16x8 av1 = *(const bf16x8*)(vb1 + ((ks * 32 + hi * 16) ^ swz));
              ot0 = __builtin_amdgcn_mfma_f32_32x32x16_bf16(av0, pw, ot0, 0, 0, 0);
              ot1 = __builtin_amdgcn_mfma_f32_32x32x16_bf16(av1, pw, ot1, 0, 0, 0);
            }
          }
          __builtin_amdgcn_s_setprio(0);
        }
      }
      __builtin_amdgcn_sched_barrier(0);
    }

    // ---- combine half-local l, normalize, store ----
    float lf = l + __shfl_xor(l, 32);
    float inv = 1.f / lf;
    unsigned short* yrow = y + ((size_t)b * T_ + q0 + col) * C_ + h * D_;
    #pragma unroll
    for (int a = 0; a < 4; ++a) {
      ushort4 o4;
      o4.x = f2bf(ot0[4 * a + 0] * inv);
      o4.y = f2bf(ot0[4 * a + 1] * inv);
      o4.z = f2bf(ot0[4 * a + 2] * inv);
      o4.w = f2bf(ot0[4 * a + 3] * inv);
      *(ushort4*)(yrow + 8 * a + 4 * hi) = o4;
    }
    #pragma unroll
    for (int a = 0; a < 4; ++a) {
      ushort4 o4;
      o4.x = f2bf(ot1[4 * a + 0] * inv);
      o4.y = f2bf(ot1[4 * a + 1] * inv);
      o4.z = f2bf(ot1[4 * a + 2] * inv);
      o4.w = f2bf(ot1[4 * a + 3] * inv);
      *(ushort4*)(yrow + 32 + 8 * a + 4 * hi) = o4;
    }
    // stores count in vmcnt: drain so next phase's manual counts stay exact
    asm volatile("s_waitcnt vmcnt(0)" ::: "memory");
  }
}

extern "C" void kernel_launch(void* const* d_in, const int* in_sizes, int n_in,
                              void* d_out, int out_size, void* d_ws, size_t ws_size,
                              hipStream_t stream) {
  const float* x  = (const float*)d_in[0];
  const float* Wq = (const float*)d_in[1];
  const float* bq = (const float*)d_in[2];
  const float* Wk = (const float*)d_in[3];
  const float* bk = (const float*)d_in[4];
  const float* Wv = (const float*)d_in[5];
  const float* bv = (const float*)d_in[6];
  const float* Wp = (const float*)d_in[7];
  const float* bp = (const float*)d_in[8];
  float* out = (float*)d_out;

  char* ws = (char*)d_ws;
  unsigned short* xb    = (unsigned short*)ws; ws += (size_t)M_ * C_ * 2;
  unsigned short* wqkvt = (unsigned short*)ws; ws += (size_t)3 * C_ * C_ * 2;
  unsigned short* wpt   = (unsigned short*)ws; ws += (size_t)C_ * C_ * 2;
  unsigned short* qb    = (unsigned short*)ws; ws += (size_t)M_ * C_ * 2;
  unsigned short* kb    = (unsigned short*)ws; ws += (size_t)M_ * C_ * 2;
  unsigned short* vtb   = (unsigned short*)ws; ws += (size_t)M_ * C_ * 2;
  unsigned short* yb    = (unsigned short*)ws; ws += (size_t)M_ * C_ * 2;

  cvt_f32_bf16<<<dim3((M_ * C_ / 4 + 255) / 256), dim3(256), 0, stream>>>(x, xb, M_ * C_ / 4);
  transpose_cvt<<<dim3(32, 32, 4), dim3(32, 8), 0, stream>>>(Wq, Wk, Wv, Wp, wqkvt, wpt);

  const float qscale = 0.125f * 1.4426950408889634f;  // 1/sqrt(64) * log2(e)
  gemm_qkv<<<dim3(3 * C_ / 128, M_ / 128), dim3(256), 0, stream>>>(
      xb, wqkvt, bq, bk, bv, qb, kb, vtb, qscale);

  attn11<<<dim3(512), dim3(256), 0, stream>>>(qb, kb, vtb, yb);

  gemm_proj<<<dim3(C_ / 128, M_ / 128), dim3(256), 0, stream>>>(yb, wpt, bp, out);
}

// Round 12
// 159.359 us; speedup vs baseline: 2.4378x; 1.0444x over previous
//
#include <hip/hip_runtime.h>
#include <hip/hip_bf16.h>

#define B_ 4
#define T_ 2048
#define C_ 1024
#define H_ 16
#define D_ 64
#define M_ (B_*T_)   // 8192

typedef __bf16 bf16x8 __attribute__((ext_vector_type(8)));
typedef float  f32x4  __attribute__((ext_vector_type(4)));
typedef float  f32x16 __attribute__((ext_vector_type(16)));

__device__ __forceinline__ unsigned short f2bf(float f) {
  unsigned u = __builtin_bit_cast(unsigned, f);
  u += 0x7FFF + ((u >> 16) & 1);   // round-to-nearest-even
  return (unsigned short)(u >> 16);
}

__device__ __forceinline__ float exp2fast(float x) {
#if __has_builtin(__builtin_amdgcn_exp2f)
  return __builtin_amdgcn_exp2f(x);
#else
  float r; asm("v_exp_f32 %0, %1" : "=v"(r) : "v"(x)); return r;
#endif
}

__device__ __forceinline__ void gload_lds16(const void* g, void* l) {
  __builtin_amdgcn_global_load_lds(
      (const __attribute__((address_space(1))) void*)g,
      (__attribute__((address_space(3))) void*)l, 16, 0, 0);
}

// ---------------- conversion: f32 -> bf16 (vectorized) ----------------
__global__ void cvt_f32_bf16(const float* __restrict__ in,
                             unsigned short* __restrict__ out, int n4) {
  int i = blockIdx.x * blockDim.x + threadIdx.x;
  if (i < n4) {
    float4 v = ((const float4*)in)[i];
    ushort4 o;
    o.x = f2bf(v.x); o.y = f2bf(v.y); o.z = f2bf(v.z); o.w = f2bf(v.w);
    ((ushort4*)out)[i] = o;
  }
}

// ------------- weight transpose + convert: W[K][N] f32 -> Wt[N][K] bf16 -------------
__global__ void transpose_cvt(const float* __restrict__ w0, const float* __restrict__ w1,
                              const float* __restrict__ w2, const float* __restrict__ w3,
                              unsigned short* __restrict__ tqkv,
                              unsigned short* __restrict__ tp) {
  __shared__ float tile[32][33];
  const float* src; unsigned short* dst;
  switch (blockIdx.z) {
    case 0: src = w0; dst = tqkv; break;
    case 1: src = w1; dst = tqkv + (size_t)C_ * C_; break;
    case 2: src = w2; dst = tqkv + (size_t)2 * C_ * C_; break;
    default: src = w3; dst = tp; break;
  }
  int bx = blockIdx.x * 32;  // n base
  int by = blockIdx.y * 32;  // k base
  int tx = threadIdx.x, ty = threadIdx.y;
  #pragma unroll
  for (int j = 0; j < 4; ++j)
    tile[ty + 8*j][tx] = src[(size_t)(by + ty + 8*j) * C_ + bx + tx];
  __syncthreads();
  #pragma unroll
  for (int j = 0; j < 4; ++j)
    dst[(size_t)(bx + ty + 8*j) * C_ + by + tx] = f2bf(tile[tx][ty + 8*j]);
}

// ---------------- fused QKV GEMM: xb[M][K] @ wqkvt[3N][K]^T ----------------
__global__ __launch_bounds__(256, 2)
void gemm_qkv(const unsigned short* __restrict__ A,
              const unsigned short* __restrict__ Bt,
              const float* __restrict__ bq, const float* __restrict__ bk,
              const float* __restrict__ bv,
              unsigned short* __restrict__ qout, unsigned short* __restrict__ kout,
              unsigned short* __restrict__ vout, float qscale)
{
  __shared__ unsigned short lsA[128 * 64];
  __shared__ unsigned short lsB[128 * 64];
  const int wave = threadIdx.x >> 6;
  const int lane = threadIdx.x & 63;
  const int rowBase = blockIdx.y * 128;
  const int colBase = blockIdx.x * 128;
  const int rowOff = (wave >> 1) * 64;
  const int colOff = (wave & 1) * 64;
  const int lr = lane & 15;
  const int lg = lane >> 4;

  f32x4 acc[4][4] = {};

  const int chunkRow = lane >> 3;
  const int srcColE  = (((lane & 7) ^ (lane >> 3)) * 8);

  for (int k0 = 0; k0 < C_; k0 += 64) {
    #pragma unroll
    for (int c = 0; c < 4; ++c) {
      int chunk = c * 4 + wave;
      int r = chunk * 8 + chunkRow;
      gload_lds16(A  + (size_t)(rowBase + r) * C_ + k0 + srcColE, &lsA[chunk * 512]);
      gload_lds16(Bt + (size_t)(colBase + r) * C_ + k0 + srcColE, &lsB[chunk * 512]);
    }
    __syncthreads();
    #pragma unroll
    for (int kk = 0; kk < 2; ++kk) {
      bf16x8 af[4], bfr[4];
      const int kbyte = (kk * 32 + lg * 8) * 2;
      #pragma unroll
      for (int m = 0; m < 4; ++m) {
        int row = rowOff + m * 16 + lr;
        af[m] = *(const bf16x8*)((const char*)lsA + row * 128 + (kbyte ^ ((row & 7) << 4)));
      }
      #pragma unroll
      for (int n = 0; n < 4; ++n) {
        int row = colOff + n * 16 + lr;
        bfr[n] = *(const bf16x8*)((const char*)lsB + row * 128 + (kbyte ^ ((row & 7) << 4)));
      }
      #pragma unroll
      for (int m = 0; m < 4; ++m)
        #pragma unroll
        for (int n = 0; n < 4; ++n)
          acc[m][n] = __builtin_amdgcn_mfma_f32_16x16x32_bf16(af[m], bfr[n], acc[m][n], 0, 0, 0);
    }
    __syncthreads();
  }

  const int mid = colBase >> 10;                 // 0=Q 1=K 2=V (block-uniform)
  const float* bias = (mid == 0) ? bq : (mid == 1) ? bk : bv;
  const float oscale = (mid == 0) ? qscale : 1.f;
  unsigned short* outp = (mid == 0) ? qout : (mid == 1) ? kout : vout;

  #pragma unroll
  for (int m = 0; m < 4; ++m) {
    int row0 = rowBase + rowOff + m * 16 + lg * 4;
    #pragma unroll
    for (int n = 0; n < 4; ++n) {
      int col = colBase + colOff + n * 16 + lr;
      int ncol = col & 1023;
      float bs = bias[ncol];
      int h = ncol >> 6, d = ncol & 63;
      if (mid == 2) {
        int b = row0 >> 11, t = row0 & 2047;
        int t2 = (t & ~12) | ((t & 4) << 1) | ((t & 8) >> 1);  // key-perm (bits 2<->3)
        ushort4 o;
        o.x = f2bf(acc[m][n][0] + bs);
        o.y = f2bf(acc[m][n][1] + bs);
        o.z = f2bf(acc[m][n][2] + bs);
        o.w = f2bf(acc[m][n][3] + bs);
        *(ushort4*)(outp + (((size_t)b * H_ + h) * D_ + d) * T_ + t2) = o;
      } else {
        #pragma unroll
        for (int j = 0; j < 4; ++j) {
          int r = row0 + j;
          int b = r >> 11, t = r & 2047;
          outp[((((size_t)b * H_ + h) * T_ + t) << 6) + d] = f2bf((acc[m][n][j] + bs) * oscale);
        }
      }
    }
  }
}

// ---------------- final projection GEMM: yb[M][K] @ wpt[N][K]^T -> f32 ----------------
__global__ __launch_bounds__(256, 2)
void gemm_proj(const unsigned short* __restrict__ A,
               const unsigned short* __restrict__ Bt,
               const float* __restrict__ bias,
               float* __restrict__ Cout)
{
  __shared__ unsigned short lsA[128 * 64];
  __shared__ unsigned short lsB[128 * 64];
  const int wave = threadIdx.x >> 6;
  const int lane = threadIdx.x & 63;
  const int rowBase = blockIdx.y * 128;
  const int colBase = blockIdx.x * 128;
  const int rowOff = (wave >> 1) * 64;
  const int colOff = (wave & 1) * 64;
  const int lr = lane & 15;
  const int lg = lane >> 4;

  f32x4 acc[4][4] = {};

  const int chunkRow = lane >> 3;
  const int srcColE  = (((lane & 7) ^ (lane >> 3)) * 8);

  for (int k0 = 0; k0 < C_; k0 += 64) {
    #pragma unroll
    for (int c = 0; c < 4; ++c) {
      int chunk = c * 4 + wave;
      int r = chunk * 8 + chunkRow;
      gload_lds16(A  + (size_t)(rowBase + r) * C_ + k0 + srcColE, &lsA[chunk * 512]);
      gload_lds16(Bt + (size_t)(colBase + r) * C_ + k0 + srcColE, &lsB[chunk * 512]);
    }
    __syncthreads();
    #pragma unroll
    for (int kk = 0; kk < 2; ++kk) {
      bf16x8 af[4], bfr[4];
      const int kbyte = (kk * 32 + lg * 8) * 2;
      #pragma unroll
      for (int m = 0; m < 4; ++m) {
        int row = rowOff + m * 16 + lr;
        af[m] = *(const bf16x8*)((const char*)lsA + row * 128 + (kbyte ^ ((row & 7) << 4)));
      }
      #pragma unroll
      for (int n = 0; n < 4; ++n) {
        int row = colOff + n * 16 + lr;
        bfr[n] = *(const bf16x8*)((const char*)lsB + row * 128 + (kbyte ^ ((row & 7) << 4)));
      }
      #pragma unroll
      for (int m = 0; m < 4; ++m)
        #pragma unroll
        for (int n = 0; n < 4; ++n)
          acc[m][n] = __builtin_amdgcn_mfma_f32_16x16x32_bf16(af[m], bfr[n], acc[m][n], 0, 0, 0);
    }
    __syncthreads();
  }

  #pragma unroll
  for (int m = 0; m < 4; ++m) {
    int row0 = rowBase + rowOff + m * 16 + lg * 4;
    #pragma unroll
    for (int n = 0; n < 4; ++n) {
      int col = colBase + colOff + n * 16 + lr;
      float bs = bias[col];
      #pragma unroll
      for (int j = 0; j < 4; ++j)
        Cout[(size_t)(row0 + j) * C_ + col] = acc[m][n][j] + bs;
    }
  }
}

// -------- causal flash attention: LDS-staged, K 3-buf / V 2-buf, counted vmcnt ----------
// q,k: [B][H][T][D] bf16 (q pre-scaled by log2e/sqrt(D)); vp: [B][H][D][T] bf16 key-permuted
// (bits 2<->3 of t swapped); y: [B][T][C] bf16.
// 1024 blocks x 4 waves: block = (head, 128-row supertile), longest-first. LDS 40KB ->
// 4 blocks/CU (16 waves/CU). Per step: wait vmcnt(2) (own tile-s loads), s_barrier, issue
// V(s+1) then K(s+2) (queue: K(s),V(s) drained, K(s+1) in flight -> uniform vmcnt(2)).
// Softmax: lane-local common path, v_exp_f32, defer-max THR=8, half-local l.
__global__ __launch_bounds__(256, 2)
void attn12(const unsigned short* __restrict__ q,
            const unsigned short* __restrict__ k,
            const unsigned short* __restrict__ vp,
            unsigned short* __restrict__ y)
{
  __shared__ unsigned short lsK[3][64 * 64];   // 24 KB
  __shared__ unsigned short lsV[2][64 * 64];   // 16 KB
  const int tid  = threadIdx.x;
  const int wave = tid >> 6;
  const int lane = tid & 63;
  const int col  = lane & 31;
  const int hi   = lane >> 5;

  const int bid = blockIdx.x;            // 0..1023
  const int xcd = bid & 7;
  const int idx = bid >> 3;              // 0..127
  const int bh  = xcd * 8 + (idx & 7);   // 8 heads per XCD
  const int ss  = 15 - (idx >> 3);       // supertile 15..0 (longest first)
  const int b = bh >> 4, h = bh & 15;

  const unsigned short* qh = q  + (size_t)bh * T_ * D_;
  const unsigned short* kh = k  + (size_t)bh * T_ * D_;
  const unsigned short* vh = vp + (size_t)bh * D_ * T_;

  // staging source (inverse-swizzled): thread t -> LDS linear 16B chunks t and t+256
  const int srow = tid >> 3;                             // 0..31
  const int srcE = ((tid & 7) * 8) ^ ((srow & 7) << 3);
  const unsigned short* ksrc = kh + srow * D_ + srcE;
  const unsigned short* vsrc = vh + srow * T_ + srcE;

  const int swz = (col & 7) << 4;
  const f32x16 zc = {};

  const int q0 = ss * 128 + wave * 32;
  const int nsteps = 2 * ss + 2;

  // Q fragments
  bf16x8 bqf[4];
  {
    const unsigned short* qrow = qh + (size_t)(q0 + col) * D_ + hi * 8;
    #pragma unroll
    for (int ks = 0; ks < 4; ++ks) bqf[ks] = *(const bf16x8*)(qrow + ks * 16);
  }

  f32x16 ot0 = {}, ot1 = {};
  float m = -INFINITY, l = 0.f;
  bf16x8 pf0, pf1, pf2, pf3;

  auto STAGEK = [&](int t) {
    unsigned short* bK = &lsK[0][0] + (t % 3) * 4096;
    const unsigned short* kg = ksrc + (size_t)t * 64 * D_;
    gload_lds16(kg,           bK + tid * 8);
    gload_lds16(kg + 32 * D_, bK + (tid + 256) * 8);
  };
  auto STAGEV = [&](int t) {
    unsigned short* bV = &lsV[0][0] + (t & 1) * 4096;
    const unsigned short* vg = vsrc + t * 64;
    gload_lds16(vg,           bV + tid * 8);
    gload_lds16(vg + 32 * T_, bV + (tid + 256) * 8);
  };

  // prologue queue (oldest->newest): K0, V0, K1
  STAGEK(0);
  STAGEV(0);
  STAGEK(1);

  for (int s = 0; s < nsteps; ++s) {
    if (s + 1 < nsteps) {
      asm volatile("s_waitcnt vmcnt(2)" ::: "memory");   // K(s),V(s) landed; K(s+1) in flight
    } else {
      asm volatile("s_waitcnt vmcnt(0)" ::: "memory");   // last step: drain
    }
    __builtin_amdgcn_s_barrier();                         // everyone's tile s landed
    __builtin_amdgcn_sched_barrier(0);
    if (s + 1 < nsteps) STAGEV(s + 1);                    // V 1 ahead (into buf of V(s-1))
    if (s + 2 < nsteps) STAGEK(s + 2);                    // K 2 ahead (into buf of K(s-1))

    const int n0 = s * 64;
    if (n0 <= q0 + 31) {
      const bool two = (n0 < q0);
      const unsigned short* baseK = &lsK[0][0] + (s % 3) * 4096;
      const unsigned short* baseV = &lsV[0][0] + (s & 1) * 4096;
      // ---- QK^T ----
      f32x16 st0, st1;
      {
        const char* kb0 = (const char*)baseK + col * 128;
        __builtin_amdgcn_s_setprio(1);
        st0 = __builtin_amdgcn_mfma_f32_32x32x16_bf16(
                *(const bf16x8*)(kb0 + ((0 * 32 + hi * 16) ^ swz)), bqf[0], zc, 0, 0, 0);
        st0 = __builtin_amdgcn_mfma_f32_32x32x16_bf16(
                *(const bf16x8*)(kb0 + ((1 * 32 + hi * 16) ^ swz)), bqf[1], st0, 0, 0, 0);
        st0 = __builtin_amdgcn_mfma_f32_32x32x16_bf16(
                *(const bf16x8*)(kb0 + ((2 * 32 + hi * 16) ^ swz)), bqf[2], st0, 0, 0, 0);
        st0 = __builtin_amdgcn_mfma_f32_32x32x16_bf16(
                *(const bf16x8*)(kb0 + ((3 * 32 + hi * 16) ^ swz)), bqf[3], st0, 0, 0, 0);
        if (two) {
          const char* kb1 = kb0 + 32 * 128;
          f32x16 a;
          a = __builtin_amdgcn_mfma_f32_32x32x16_bf16(
                *(const bf16x8*)(kb1 + ((0 * 32 + hi * 16) ^ swz)), bqf[0], zc, 0, 0, 0);
          a = __builtin_amdgcn_mfma_f32_32x32x16_bf16(
                *(const bf16x8*)(kb1 + ((1 * 32 + hi * 16) ^ swz)), bqf[1], a, 0, 0, 0);
          a = __builtin_amdgcn_mfma_f32_32x32x16_bf16(
                *(const bf16x8*)(kb1 + ((2 * 32 + hi * 16) ^ swz)), bqf[2], a, 0, 0, 0);
          a = __builtin_amdgcn_mfma_f32_32x32x16_bf16(
                *(const bf16x8*)(kb1 + ((3 * 32 + hi * 16) ^ swz)), bqf[3], a, 0, 0, 0);
          st1 = a;
        }
        __builtin_amdgcn_s_setprio(0);
      }
      // ---- causal mask (diagonal region only) ----
      if (n0 + 63 > q0) {
        #pragma unroll
        for (int rr = 0; rr < 16; ++rr) {
          int key0 = n0 + (rr & 3) + 8 * (rr >> 2) + 4 * hi;
          if (key0 > q0 + col) st0[rr] = -INFINITY;
          if (two) { if (key0 + 32 > q0 + col) st1[rr] = -INFINITY; }
        }
      }
      // ---- softmax (lane-local common path) ----
      float mm;
      {
        float a0 = fmaxf(fmaxf(st0[0], st0[1]), fmaxf(st0[2], st0[3]));
        float a1 = fmaxf(fmaxf(st0[4], st0[5]), fmaxf(st0[6], st0[7]));
        float a2 = fmaxf(fmaxf(st0[8], st0[9]), fmaxf(st0[10], st0[11]));
        float a3 = fmaxf(fmaxf(st0[12], st0[13]), fmaxf(st0[14], st0[15]));
        if (two) {
          a0 = fmaxf(a0, fmaxf(fmaxf(st1[0], st1[1]), fmaxf(st1[2], st1[3])));
          a1 = fmaxf(a1, fmaxf(fmaxf(st1[4], st1[5]), fmaxf(st1[6], st1[7])));
          a2 = fmaxf(a2, fmaxf(fmaxf(st1[8], st1[9]), fmaxf(st1[10], st1[11])));
          a3 = fmaxf(a3, fmaxf(fmaxf(st1[12], st1[13]), fmaxf(st1[14], st1[15])));
        }
        mm = fmaxf(fmaxf(a0, a1), fmaxf(a2, a3));
      }
      if (!__all(mm <= m + 8.f)) {           // rare rescale path
        float mf = fmaxf(mm, __shfl_xor(mm, 32));
        float mnew = fmaxf(m, mf);
        float corr = exp2fast(m - mnew);
        m = mnew;
        l *= corr;
        #pragma unroll
        for (int rr = 0; rr < 16; ++rr) { ot0[rr] *= corr; ot1[rr] *= corr; }
      }
      {
        float pa[8];
        bf16x8 w;
        #pragma unroll
        for (int e = 0; e < 8; ++e) { pa[e] = exp2fast(st0[e] - m); w[e] = (__bf16)pa[e]; }
        pf0 = w;
        l += ((pa[0] + pa[1]) + (pa[2] + pa[3])) + ((pa[4] + pa[5]) + (pa[6] + pa[7]));
      }
      {
        float pb[8];
        bf16x8 w;
        #pragma unroll
        for (int e = 0; e < 8; ++e) { pb[e] = exp2fast(st0[8 + e] - m); w[e] = (__bf16)pb[e]; }
        pf1 = w;
        l += ((pb[0] + pb[1]) + (pb[2] + pb[3])) + ((pb[4] + pb[5]) + (pb[6] + pb[7]));
      }
      if (two) {
        float pa[8];
        bf16x8 w;
        #pragma unroll
        for (int e = 0; e < 8; ++e) { pa[e] = exp2fast(st1[e] - m); w[e] = (__bf16)pa[e]; }
        pf2 = w;
        l += ((pa[0] + pa[1]) + (pa[2] + pa[3])) + ((pa[4] + pa[5]) + (pa[6] + pa[7]));
        float pb[8];
        #pragma unroll
        for (int e = 0; e < 8; ++e) { pb[e] = exp2fast(st1[8 + e] - m); w[e] = (__bf16)pb[e]; }
        pf3 = w;
        l += ((pb[0] + pb[1]) + (pb[2] + pb[3])) + ((pb[4] + pb[5]) + (pb[6] + pb[7]));
      }
      // ---- PV ----
      {
        const char* vb0 = (const char*)baseV + col * 128;
        const char* vb1 = vb0 + 32 * 128;
        __builtin_amdgcn_s_setprio(1);
        #pragma unroll
        for (int ks = 0; ks < 2; ++ks) {
          bf16x8 pw = ks ? pf1 : pf0;
          bf16x8 av0 = *(const bf16x8*)(vb0 + ((ks * 32 + hi * 16) ^ swz));
          bf16x8 av1 = *(const bf16x8*)(vb1 + ((ks * 32 + hi * 16) ^ swz));
          ot0 = __builtin_amdgcn_mfma_f32_32x32x16_bf16(av0, pw, ot0, 0, 0, 0);
          ot1 = __builtin_amdgcn_mfma_f32_32x32x16_bf16(av1, pw, ot1, 0, 0, 0);
        }
        if (two) {
          #pragma unroll
          for (int ks = 2; ks < 4; ++ks) {
            bf16x8 pw = (ks == 3) ? pf3 : pf2;
            bf16x8 av0 = *(const bf16x8*)(vb0 + ((ks * 32 + hi * 16) ^ swz));
            bf16x8 av1 = *(const bf16x8*)(vb1 + ((ks * 32 + hi * 16) ^ swz));
            ot0 = __builtin_amdgcn_mfma_f32_32x32x16_bf16(av0, pw, ot0, 0, 0, 0);
            ot1 = __builtin_amdgcn_mfma_f32_32x32x16_bf16(av1, pw, ot1, 0, 0, 0);
          }
        }
        __builtin_amdgcn_s_setprio(0);
      }
    }
    __builtin_amdgcn_sched_barrier(0);
  }

  // ---- combine half-local l, normalize, store ----
  float lf = l + __shfl_xor(l, 32);
  float inv = 1.f / lf;
  unsigned short* yrow = y + ((size_t)b * T_ + q0 + col) * C_ + h * D_;
  #pragma unroll
  for (int a = 0; a < 4; ++a) {
    ushort4 o4;
    o4.x = f2bf(ot0[4 * a + 0] * inv);
    o4.y = f2bf(ot0[4 * a + 1] * inv);
    o4.z = f2bf(ot0[4 * a + 2] * inv);
    o4.w = f2bf(ot0[4 * a + 3] * inv);
    *(ushort4*)(yrow + 8 * a + 4 * hi) = o4;
  }
  #pragma unroll
  for (int a = 0; a < 4; ++a) {
    ushort4 o4;
    o4.x = f2bf(ot1[4 * a + 0] * inv);
    o4.y = f2bf(ot1[4 * a + 1] * inv);
    o4.z = f2bf(ot1[4 * a + 2] * inv);
    o4.w = f2bf(ot1[4 * a + 3] * inv);
    *(ushort4*)(yrow + 32 + 8 * a + 4 * hi) = o4;
  }
}

extern "C" void kernel_launch(void* const* d_in, const int* in_sizes, int n_in,
                              void* d_out, int out_size, void* d_ws, size_t ws_size,
                              hipStream_t stream) {
  const float* x  = (const float*)d_in[0];
  const float* Wq = (const float*)d_in[1];
  const float* bq = (const float*)d_in[2];
  const float* Wk = (const float*)d_in[3];
  const float* bk = (const float*)d_in[4];
  const float* Wv = (const float*)d_in[5];
  const float* bv = (const float*)d_in[6];
  const float* Wp = (const float*)d_in[7];
  const float* bp = (const float*)d_in[8];
  float* out = (float*)d_out;

  char* ws = (char*)d_ws;
  unsigned short* xb    = (unsigned short*)ws; ws += (size_t)M_ * C_ * 2;
  unsigned short* wqkvt = (unsigned short*)ws; ws += (size_t)3 * C_ * C_ * 2;
  unsigned short* wpt   = (unsigned short*)ws; ws += (size_t)C_ * C_ * 2;
  unsigned short* qb    = (unsigned short*)ws; ws += (size_t)M_ * C_ * 2;
  unsigned short* kb    = (unsigned short*)ws; ws += (size_t)M_ * C_ * 2;
  unsigned short* vtb   = (unsigned short*)ws; ws += (size_t)M_ * C_ * 2;
  unsigned short* yb    = (unsigned short*)ws; ws += (size_t)M_ * C_ * 2;

  cvt_f32_bf16<<<dim3((M_ * C_ / 4 + 255) / 256), dim3(256), 0, stream>>>(x, xb, M_ * C_ / 4);
  transpose_cvt<<<dim3(32, 32, 4), dim3(32, 8), 0, stream>>>(Wq, Wk, Wv, Wp, wqkvt, wpt);

  const float qscale = 0.125f * 1.4426950408889634f;  // 1/sqrt(64) * log2(e)
  gemm_qkv<<<dim3(3 * C_ / 128, M_ / 128), dim3(256), 0, stream>>>(
      xb, wqkvt, bq, bk, bv, qb, kb, vtb, qscale);

  attn12<<<dim3(1024), dim3(256), 0, stream>>>(qb, kb, vtb, yb);

  gemm_proj<<<dim3(C_ / 128, M_ / 128), dim3(256), 0, stream>>>(yb, wpt, bp, out);
}